// Round 1
// 907.444 us; speedup vs baseline: 1.1584x; 1.1584x over previous
//
#include <hip/hip_runtime.h>

#define NN   12000
#define NE   384000
#define FIN  512
#define FHID 256
#define FOUT 64

typedef unsigned short u16;
typedef __attribute__((ext_vector_type(8))) short  s8v;   // 8 x bf16 (4 VGPRs) MFMA operand
typedef __attribute__((ext_vector_type(4))) float  f4v;   // MFMA accumulator / float4

__device__ __forceinline__ u16 f2bf(float f) {
    union { float f; unsigned int i; } v; v.f = f;
    return (u16)((v.i + 0x7FFFu + ((v.i >> 16) & 1u)) >> 16);   // RNE
}

// ---------------- graph preprocessing ----------------

__global__ void k_deg(const int* __restrict__ col, float* __restrict__ deg) {
    int e = blockIdx.x * 256 + threadIdx.x;
    if (e < NE) atomicAdd(&deg[col[e]], 1.0f);
}

// single-block scan of degrees -> CSR offsets; dinv = rsqrt(deg_edges + 1) (self-loop)
__global__ __launch_bounds__(1024) void k_scan(const float* __restrict__ deg,
                                               float* __restrict__ dinv,
                                               int* __restrict__ offs,
                                               int* __restrict__ cursor) {
    __shared__ int sh[1024];
    int tid = threadIdx.x;
    int base = tid * 12;
    int loc[12];
    int sum = 0;
    for (int j = 0; j < 12; j++) {
        int i = base + j;
        int d = (i < NN) ? (int)deg[i] : 0;
        loc[j] = sum;
        sum += d;
    }
    sh[tid] = sum;
    __syncthreads();
    for (int off = 1; off < 1024; off <<= 1) {
        int v = (tid >= off) ? sh[tid - off] : 0;
        __syncthreads();
        sh[tid] += v;
        __syncthreads();
    }
    int prev = (tid == 0) ? 0 : sh[tid - 1];
    for (int j = 0; j < 12; j++) {
        int i = base + j;
        if (i < NN) {
            int o = prev + loc[j];
            offs[i] = o;
            cursor[i] = o;
            dinv[i] = rsqrtf(deg[i] + 1.0f);
        }
    }
    if (tid == 0) offs[NN] = NE;
}

__global__ void k_fill(const int* __restrict__ row, const int* __restrict__ col,
                       int* __restrict__ cursor, int* __restrict__ csr) {
    int e = blockIdx.x * 256 + threadIdx.x;
    if (e < NE) {
        int c = col[e];
        int p = atomicAdd(&cursor[c], 1);
        csr[p] = row[e];
    }
}

// ---------------- weight repack: fp32 B[K][N] -> bf16 per-(tile,kstep,lane) 8-elem frags ----
__global__ void k_repack(const float* __restrict__ B, u16* __restrict__ Bp, int K, int N) {
    int idx = blockIdx.x * 256 + threadIdx.x;
    int total = (N >> 4) * (K >> 5) * 64;
    if (idx >= total) return;
    int l  = idx & 63;
    int ts = idx >> 6;
    int Ks = K >> 5;
    int s  = ts % Ks;
    int t  = ts / Ks;
    int q = l >> 4, r = l & 15;
    s8v v;
    #pragma unroll
    for (int j = 0; j < 8; j++)
        v[j] = (short)f2bf(B[(s * 32 + q * 8 + j) * N + t * 16 + r]);
    ((s8v*)Bp)[idx] = v;
}

// ---------------- GEMM: C[m][n] = dinv[m] * sum_k A[m][k]*B[k][n]; fp32 A/C, bf16 MFMA ----
// Operand-swapped mfma(b, a, acc): lane (q,r) holds C[row0+r][tile*16 + q*4 .. +3]
// -> f4v epilogue store, single dinv load per lane.
template <int K, int N>
__global__ __launch_bounds__(256) void k_gemm(const float* __restrict__ A,
                                              const u16* __restrict__ Bp,
                                              const float* __restrict__ dinv,
                                              float* __restrict__ C) {
    constexpr int KS = K / 32;
    int wave = threadIdx.x >> 6, lane = threadIdx.x & 63;
    int q = lane >> 4, r = lane & 15;
    int row0 = blockIdx.x * 64 + wave * 16;
    if (row0 >= NN) return;                    // wave-uniform guard (NN % 16 == 0)
    int tb = blockIdx.y * 4;

    f4v acc[4];
    #pragma unroll
    for (int t = 0; t < 4; t++) acc[t] = (f4v){0.f, 0.f, 0.f, 0.f};

    const float* arow = A + (size_t)(row0 + r) * K + q * 8;
    #pragma unroll 4
    for (int s = 0; s < KS; s++) {
        f4v f0 = *(const f4v*)(arow + s * 32);
        f4v f1 = *(const f4v*)(arow + s * 32 + 4);
        s8v a;
        #pragma unroll
        for (int j = 0; j < 4; j++) { a[j] = (short)f2bf(f0[j]); a[4 + j] = (short)f2bf(f1[j]); }
        #pragma unroll
        for (int t = 0; t < 4; t++) {
            s8v b = *(const s8v*)(Bp + ((((size_t)(tb + t) * KS + s) * 64 + lane) << 3));
            acc[t] = __builtin_amdgcn_mfma_f32_16x16x32_bf16(b, a, acc[t], 0, 0, 0);
        }
    }
    float dv = dinv[row0 + r];
    float* crow = C + (size_t)(row0 + r) * N;
    #pragma unroll
    for (int t = 0; t < 4; t++) {
        f4v ov = acc[t] * dv;
        *(f4v*)(crow + (tb + t) * 16 + q * 4) = ov;
    }
}

// ---------------- aggregation (F=256): out[c] = relu?(dinv[c]*(sum_nb + self) + b) -------
// Edge loop unrolled 4-wide: 4 independent gather loads in flight per waitcnt.
template <bool RELU>
__global__ __launch_bounds__(256) void k_agg(const float* __restrict__ hw,
                                             const int* __restrict__ csr,
                                             const int* __restrict__ offs,
                                             const float* __restrict__ dinv,
                                             const float* __restrict__ bias,
                                             float* __restrict__ out) {
    constexpr int F = 256;
    int wg = (blockIdx.x * 256 + threadIdx.x) >> 6;
    if (wg >= NN) return;
    int lane = threadIdx.x & 63;
    int c = wg;
    const float* hp = hw + lane * 4;

    f4v acc = *(const f4v*)(hp + (size_t)c * F);   // self-loop term
    int beg = offs[c], end = offs[c + 1];
    for (int e = beg; e < end; e += 64) {
        int nb = end - e; if (nb > 64) nb = 64;
        int myid = (e + lane < end) ? csr[e + lane] : 0;
        int j = 0;
        for (; j + 4 <= nb; j += 4) {
            int s0 = __shfl(myid, j, 64);
            int s1 = __shfl(myid, j + 1, 64);
            int s2 = __shfl(myid, j + 2, 64);
            int s3 = __shfl(myid, j + 3, 64);
            f4v v0 = *(const f4v*)(hp + (size_t)s0 * F);
            f4v v1 = *(const f4v*)(hp + (size_t)s1 * F);
            f4v v2 = *(const f4v*)(hp + (size_t)s2 * F);
            f4v v3 = *(const f4v*)(hp + (size_t)s3 * F);
            v0 += v1; v2 += v3;
            acc += v0 + v2;
        }
        for (; j < nb; j++) {
            int s0 = __shfl(myid, j, 64);
            acc += *(const f4v*)(hp + (size_t)s0 * F);
        }
    }
    float dv = dinv[c];
    f4v bv = *(const f4v*)(bias + lane * 4);
    f4v ov = acc * dv + bv;
    if (RELU) {
        #pragma unroll
        for (int k = 0; k < 4; k++) ov[k] = fmaxf(ov[k], 0.f);
    }
    *(f4v*)(out + (size_t)c * F + lane * 4) = ov;
}

// ---------------- mu aggregation (F=64): fp32 gather-sum, bf16 row-major output ------------
__global__ __launch_bounds__(256) void k_agg_mu(const float* __restrict__ hw,
                                                const int* __restrict__ csr,
                                                const int* __restrict__ offs,
                                                const float* __restrict__ dinv,
                                                const float* __restrict__ bias,
                                                u16* __restrict__ out) {
    constexpr int F = 64;
    int wg = (blockIdx.x * 256 + threadIdx.x) >> 6;
    if (wg >= NN) return;
    int lane = threadIdx.x & 63;
    int c = wg;
    const float* hp = hw + lane;

    float acc = hp[(size_t)c * F];
    int beg = offs[c], end = offs[c + 1];
    for (int e = beg; e < end; e += 64) {
        int nb = end - e; if (nb > 64) nb = 64;
        int myid = (e + lane < end) ? csr[e + lane] : 0;
        int j = 0;
        for (; j + 4 <= nb; j += 4) {
            int s0 = __shfl(myid, j, 64);
            int s1 = __shfl(myid, j + 1, 64);
            int s2 = __shfl(myid, j + 2, 64);
            int s3 = __shfl(myid, j + 3, 64);
            float v0 = hp[(size_t)s0 * F];
            float v1 = hp[(size_t)s1 * F];
            float v2 = hp[(size_t)s2 * F];
            float v3 = hp[(size_t)s3 * F];
            acc += (v0 + v1) + (v2 + v3);
        }
        for (; j < nb; j++)
            acc += hp[(size_t)__shfl(myid, j, 64) * F];
    }
    out[(size_t)c * F + lane] = f2bf(acc * dinv[c] + bias[lane]);
}

// ---------------- decoder: out = sigmoid(mu @ mu^T), bf16-packed mu in, fp32 out -----------
// Operand-swapped mfma(b, a, acc): lane (q,r) holds C[row0+r][n0 + q*4 .. +3] -> f4v stores.
__global__ __launch_bounds__(256) void k_dec(const u16* __restrict__ mu, float* __restrict__ out) {
    int wave = threadIdx.x >> 6, lane = threadIdx.x & 63;
    int q = lane >> 4, r = lane & 15;
    int row0 = blockIdx.y * 64 + wave * 16;
    if (row0 >= NN) return;
    int col0 = blockIdx.x * 64;

    const u16* ap = mu + (size_t)(row0 + r) * FOUT + q * 8;
    s8v a0 = *(const s8v*)(ap);
    s8v a1 = *(const s8v*)(ap + 32);
    float* orow = out + (size_t)(row0 + r) * NN;

    #pragma unroll
    for (int t = 0; t < 4; t++) {
        int n0 = col0 + t * 16;
        if (n0 >= NN) return;     // tiles increase monotonically
        const u16* bp = mu + (size_t)(n0 + r) * FOUT + q * 8;
        s8v b0 = *(const s8v*)(bp);
        s8v b1 = *(const s8v*)(bp + 32);
        f4v acc = (f4v){0.f, 0.f, 0.f, 0.f};
        acc = __builtin_amdgcn_mfma_f32_16x16x32_bf16(b0, a0, acc, 0, 0, 0);
        acc = __builtin_amdgcn_mfma_f32_16x16x32_bf16(b1, a1, acc, 0, 0, 0);
        f4v ov;
        #pragma unroll
        for (int rr = 0; rr < 4; rr++) {
            float e = __expf(-acc[rr]);
            ov[rr] = __builtin_amdgcn_rcpf(1.0f + e);   // v_rcp_f32: ~1 ulp, fine at 4e-3 tol
        }
        *(f4v*)(orow + n0 + q * 4) = ov;
    }
}

// ---------------- launch ----------------
extern "C" void kernel_launch(void* const* d_in, const int* in_sizes, int n_in,
                              void* d_out, int out_size, void* d_ws, size_t ws_size,
                              hipStream_t stream) {
    const float* x   = (const float*)d_in[0];
    const int*   ei  = (const int*)d_in[1];        // [2*E]: row then col (int32 — jax x64 off)
    const float* W1  = (const float*)d_in[2];
    const float* b1  = (const float*)d_in[3];
    const float* W2  = (const float*)d_in[4];
    const float* b2  = (const float*)d_in[5];
    const float* Wmu = (const float*)d_in[6];
    const float* bmu = (const float*)d_in[7];
    // d_in[8], d_in[9] (Wls, bls): dead — z = mu in eval mode.

    char* w = (char*)d_ws;
    size_t off = 0;
    auto alloc = [&](size_t bytes) {
        void* p = w + off;
        off = (off + bytes + 255) & ~(size_t)255;
        return p;
    };
    float* deg    = (float*)alloc(NN * 4);
    float* dinv   = (float*)alloc(NN * 4);
    int*   offs   = (int*)alloc((NN + 1) * 4);
    int*   cursor = (int*)alloc(NN * 4);
    int*   csr    = (int*)alloc(NE * 4);
    float* hw     = (float*)alloc((size_t)NN * FHID * 4);   // GEMM outputs (max width 256)
    float* hA     = (float*)alloc((size_t)NN * FHID * 4);
    float* hB     = (float*)alloc((size_t)NN * FHID * 4);
    u16*   muB    = (u16*)alloc((size_t)NN * FOUT * 2);     // bf16-packed mu for decoder
    u16*   W1p    = (u16*)alloc((size_t)FIN * FHID * 2);
    u16*   W2p    = (u16*)alloc((size_t)FHID * FHID * 2);
    u16*   Wmp    = (u16*)alloc((size_t)FHID * FOUT * 2);

    const int* erow = ei;
    const int* ecol = ei + NE;

    hipMemsetAsync(deg, 0, NN * 4, stream);
    k_deg<<<(NE + 255) / 256, 256, 0, stream>>>(ecol, deg);
    k_scan<<<1, 1024, 0, stream>>>(deg, dinv, offs, cursor);
    k_fill<<<(NE + 255) / 256, 256, 0, stream>>>(erow, ecol, cursor, csr);

    k_repack<<<((FIN / 32) * (FHID / 16) * 64 + 255) / 256, 256, 0, stream>>>(W1, W1p, FIN, FHID);
    k_repack<<<((FHID / 32) * (FHID / 16) * 64 + 255) / 256, 256, 0, stream>>>(W2, W2p, FHID, FHID);
    k_repack<<<((FHID / 32) * (FOUT / 16) * 64 + 255) / 256, 256, 0, stream>>>(Wmu, Wmp, FHID, FOUT);

    dim3 blk(256);
    // layer 1: hw' = dinv .* (x @ W1); h1 = relu(dinv .* (gather-sum + self) + b1)
    k_gemm<FIN, FHID><<<dim3(188, FHID / 64), blk, 0, stream>>>(x, W1p, dinv, hw);
    k_agg<true><<<NN / 4, blk, 0, stream>>>(hw, csr, offs, dinv, b1, hA);
    // layer 2
    k_gemm<FHID, FHID><<<dim3(188, FHID / 64), blk, 0, stream>>>(hA, W2p, dinv, hw);
    k_agg<true><<<NN / 4, blk, 0, stream>>>(hw, csr, offs, dinv, b2, hB);
    // mu head: GEMM fp32 out, aggregation emits bf16-packed mu directly
    k_gemm<FHID, FOUT><<<dim3(188, FOUT / 64), blk, 0, stream>>>(hB, Wmp, dinv, hw);
    k_agg_mu<<<NN / 4, blk, 0, stream>>>(hw, csr, offs, dinv, bmu, muB);
    // decoder
    k_dec<<<dim3(188, 188), blk, 0, stream>>>(muB, (float*)d_out);
}